// Round 5
// baseline (98.943 us; speedup 1.0000x reference)
//
#include <hip/hip_runtime.h>
#include <hip/hip_bf16.h>
#include <math.h>

typedef __attribute__((ext_vector_type(8))) short short8v;  // 8 bf16 in 4 VGPRs
typedef __attribute__((ext_vector_type(4))) float f32x4;

__device__ inline unsigned short f2bf(float f) {
  return __builtin_bit_cast(unsigned short, __float2bfloat16(f));
}

// ---------------------------------------------------------------------------
// fold_kernel: single block, 1024 threads. Computes the folded fp32 matrices
// in LDS, then emits the bf16 weight fragments PRE-PACKED in the exact
// per-lane MFMA layout: wsbf[lane][frag 0..17][elem 0..7] bf16.
//   frags 0..5  : hAf[go][f]   (go=frag>>1, f=frag&1), elem e -> hA[(16go+r)*64 + 32f + 8c + e]
//   frags 6..11 : gAf[go][f]   same mapping from gA
//   frags 12..17: w2f[go][f]   delta-permuted W2 (+ b2 in frag f=1, elem 4)
// where r=lane&15, c=lane>>4. k=60 of hA/gA holds the bias (consumed by a
// 1.0 input in the c==3 lane group).
// ---------------------------------------------------------------------------
#define SH_HA 0
#define SH_GA 3072
#define SH_W2 6144
#define SH_B2 9216
#define SH_TOTAL 9264

__global__ __launch_bounds__(1024) void fold_kernel(
    const float* __restrict__ Wiv, const float* __restrict__ biv,
    const float* __restrict__ Wtv, const float* __restrict__ btv,
    const float* __restrict__ Wisv, const float* __restrict__ bisv,
    const float* __restrict__ Wtsv, const float* __restrict__ btsv,
    const float* __restrict__ Wm1, const float* __restrict__ bm1,
    const float* __restrict__ Wm2, const float* __restrict__ bm2,
    const float* __restrict__ Wg, const float* __restrict__ bg,
    unsigned short* __restrict__ wsbf) {
  __shared__ float s[SH_TOTAL];
  const int tid = threadIdx.x;

  for (int idx = tid; idx < 48 * 64; idx += 1024) {
    int o = idx >> 6, j = idx & 63;
    float acc = 0.f;
    if (j < 40) {
      for (int k = 0; k < 48; ++k) acc += Wm1[o * 144 + 48 + k] * Wtv[k * 40 + j];
      for (int k = 0; k < 24; ++k) acc += Wm1[o * 144 + 96 + k] * Wisv[k * 40 + j];
    } else if (j < 60) {
      int jj = j - 40;
      for (int k = 0; k < 48; ++k) acc += Wm1[o * 144 + k] * Wiv[k * 20 + jj];
      for (int k = 0; k < 24; ++k) acc += Wm1[o * 144 + 120 + k] * Wtsv[k * 20 + jj];
    } else if (j == 60) {  // bias slot
      acc = bm1[o];
      for (int k = 0; k < 48; ++k) acc += Wm1[o * 144 + k] * biv[k];
      for (int k = 0; k < 48; ++k) acc += Wm1[o * 144 + 48 + k] * btv[k];
      for (int k = 0; k < 24; ++k) acc += Wm1[o * 144 + 96 + k] * bisv[k];
      for (int k = 0; k < 24; ++k) acc += Wm1[o * 144 + 120 + k] * btsv[k];
    }
    s[SH_HA + idx] = acc;
  }
  for (int idx = tid; idx < 48 * 64; idx += 1024) {
    int o = idx >> 6, j = idx & 63;
    float acc = 0.f;
    if (j < 40) {
      for (int k = 0; k < 48; ++k) acc += Wg[o * 96 + 48 + k] * Wtv[k * 40 + j];
    } else if (j < 60) {
      int jj = j - 40;
      for (int k = 0; k < 48; ++k) acc += Wg[o * 96 + k] * Wiv[k * 20 + jj];
    } else if (j == 60) {
      acc = bg[o];
      for (int k = 0; k < 48; ++k) acc += Wg[o * 96 + k] * biv[k];
      for (int k = 0; k < 48; ++k) acc += Wg[o * 96 + 48 + k] * btv[k];
    }
    s[SH_GA + idx] = acc;
  }
  for (int idx = tid; idx < 48 * 64; idx += 1024) {
    int o = idx >> 6, k = idx & 63;
    s[SH_W2 + idx] = (k < 48) ? Wm2[o * 48 + k] : 0.f;
  }
  for (int o = tid; o < 48; o += 1024) s[SH_B2 + o] = bm2[o];

  __syncthreads();

  // pack phase: 64 lanes x 18 frags x 8 elems = 9216 bf16
  for (int idx = tid; idx < 64 * 18 * 8; idx += 1024) {
    const int lane = idx / 144;
    const int f18 = (idx >> 3) % 18;
    const int e = idx & 7;
    const int r = lane & 15, c = lane >> 4;
    float v;
    if (f18 < 12) {
      const int q = (f18 < 6) ? f18 : f18 - 6;
      const int base = (f18 < 6) ? SH_HA : SH_GA;
      const int go = q >> 1, f = q & 1;
      v = s[base + (go * 16 + r) * 64 + f * 32 + c * 8 + e];
    } else {
      const int q = f18 - 12;
      const int go = q >> 1, f = q & 1;
      const int row = go * 16 + r;
      if (f == 0) {
        v = s[SH_W2 + row * 64 + ((e < 4) ? (4 * c + e) : (16 + 4 * c + (e - 4)))];
      } else {
        v = (e < 4) ? s[SH_W2 + row * 64 + 32 + 4 * c + e]
                    : ((e == 4) ? s[SH_B2 + row] : 0.f);
      }
    }
    wsbf[idx] = f2bf(v);
  }
}

// ---------------------------------------------------------------------------
// mfma_main: 256 threads = 4 waves, 32 rows/wave (2 tiles of 16), grid 2048.
// Weights arrive pre-packed (18 x 16B loads, no conversion VALU) and stay
// VGPR-resident (launch_bounds(256,3) -> 170-reg budget; weights = 72).
// Both tiles' X loads issue before any compute to double in-flight latency.
// No LDS, no barriers; waves fully independent.
// ---------------------------------------------------------------------------
__device__ __forceinline__ short8v packX(float4 a, float4 b) {
  short8v sv;
  sv[0] = (short)f2bf(a.x); sv[1] = (short)f2bf(a.y);
  sv[2] = (short)f2bf(a.z); sv[3] = (short)f2bf(a.w);
  sv[4] = (short)f2bf(b.x); sv[5] = (short)f2bf(b.y);
  sv[6] = (short)f2bf(b.z); sv[7] = (short)f2bf(b.w);
  return sv;
}

__device__ __forceinline__ void compute_tile(
    int rowbase, int r, int c,
    float4 i0, float4 i1, float4 b0, float4 b1,
    const short8v (&hAf)[3][2], const short8v (&gAf)[3][2],
    const short8v (&w2f)[3][2], float* __restrict__ out) {
  const f32x4 z = {0.f, 0.f, 0.f, 0.f};
  short8v xa0 = packX(i0, i1);
  short8v xa1 = packX(b0, b1);

  f32x4 hacc[3], gacc[3];
#pragma unroll
  for (int go = 0; go < 3; ++go)
    hacc[go] = __builtin_amdgcn_mfma_f32_16x16x32_bf16(
        hAf[go][1], xa1,
        __builtin_amdgcn_mfma_f32_16x16x32_bf16(hAf[go][0], xa0, z, 0, 0, 0),
        0, 0, 0);
#pragma unroll
  for (int go = 0; go < 3; ++go)
    gacc[go] = __builtin_amdgcn_mfma_f32_16x16x32_bf16(
        gAf[go][1], xa1,
        __builtin_amdgcn_mfma_f32_16x16x32_bf16(gAf[go][0], xa0, z, 0, 0, 0),
        0, 0, 0);

  short8v hb0, hb1;
#pragma unroll
  for (int j = 0; j < 4; ++j) {
    hb0[j]     = (short)f2bf(fmaxf(hacc[0][j], 0.f));
    hb0[j + 4] = (short)f2bf(fmaxf(hacc[1][j], 0.f));
    hb1[j]     = (short)f2bf(fmaxf(hacc[2][j], 0.f));
  }
  hb1[4] = (c == 3) ? (short)0x3F80 : (short)0;  // bias-1.0 in exactly one k-slot
  hb1[5] = 0; hb1[6] = 0; hb1[7] = 0;

  f32x4 oacc[3];
#pragma unroll
  for (int go = 0; go < 3; ++go)
    oacc[go] = __builtin_amdgcn_mfma_f32_16x16x32_bf16(
        w2f[go][1], hb1,
        __builtin_amdgcn_mfma_f32_16x16x32_bf16(w2f[go][0], hb0, z, 0, 0, 0),
        0, 0, 0);

  float* orow = out + (size_t)(rowbase + r) * 48;
#pragma unroll
  for (int go = 0; go < 3; ++go) {
    float4 v;
    v.x = fmaxf(oacc[go][0], 0.f) * __builtin_amdgcn_rcpf(1.f + __expf(-gacc[go][0]));
    v.y = fmaxf(oacc[go][1], 0.f) * __builtin_amdgcn_rcpf(1.f + __expf(-gacc[go][1]));
    v.z = fmaxf(oacc[go][2], 0.f) * __builtin_amdgcn_rcpf(1.f + __expf(-gacc[go][2]));
    v.w = fmaxf(oacc[go][3], 0.f) * __builtin_amdgcn_rcpf(1.f + __expf(-gacc[go][3]));
    *reinterpret_cast<float4*>(orow + 16 * go + 4 * c) = v;
  }
}

__global__ __launch_bounds__(256, 3) void mfma_main(
    const float* __restrict__ img, const float* __restrict__ txt,
    const unsigned short* __restrict__ wsbf, float* __restrict__ out) {
  const int tid = threadIdx.x;
  const int wave = tid >> 6;
  const int lane = tid & 63;
  const int r = lane & 15;
  const int c = lane >> 4;

  // resident pre-packed weight fragments: 18 x 16B contiguous per lane
  const short8v* wp = reinterpret_cast<const short8v*>(wsbf) + lane * 18;
  short8v hAf[3][2], gAf[3][2], w2f[3][2];
#pragma unroll
  for (int go = 0; go < 3; ++go) {
    hAf[go][0] = wp[go * 2 + 0];      hAf[go][1] = wp[go * 2 + 1];
    gAf[go][0] = wp[6 + go * 2 + 0];  gAf[go][1] = wp[6 + go * 2 + 1];
    w2f[go][0] = wp[12 + go * 2 + 0]; w2f[go][1] = wp[12 + go * 2 + 1];
  }

  const int base = blockIdx.x * 128 + wave * 32;  // 2 tiles of 16 rows

  // ---- issue ALL X loads for both tiles before any compute ----
  const float* pimg0 = img + (size_t)(base + r) * 40;
  const float* ptxt0 = txt + (size_t)(base + r) * 20;
  const float* pimg1 = pimg0 + 16 * 40;
  const float* ptxt1 = ptxt0 + 16 * 20;

  float4 a_i0 = *(const float4*)(pimg0 + c * 8);
  float4 a_i1 = *(const float4*)(pimg0 + c * 8 + 4);
  float4 b_i0 = *(const float4*)(pimg1 + c * 8);
  float4 b_i1 = *(const float4*)(pimg1 + c * 8 + 4);
  float4 a_b0, a_b1, b_b0, b_b1;
  if (c == 0) {
    a_b0 = *(const float4*)(pimg0 + 32); a_b1 = *(const float4*)(pimg0 + 36);
    b_b0 = *(const float4*)(pimg1 + 32); b_b1 = *(const float4*)(pimg1 + 36);
  } else if (c == 3) {
    a_b0 = *(const float4*)(ptxt0 + 16); b_b0 = *(const float4*)(ptxt1 + 16);
    a_b1 = make_float4(1.f, 0.f, 0.f, 0.f); b_b1 = make_float4(1.f, 0.f, 0.f, 0.f);
  } else {
    a_b0 = *(const float4*)(ptxt0 + (c - 1) * 8);
    a_b1 = *(const float4*)(ptxt0 + (c - 1) * 8 + 4);
    b_b0 = *(const float4*)(ptxt1 + (c - 1) * 8);
    b_b1 = *(const float4*)(ptxt1 + (c - 1) * 8 + 4);
  }

  compute_tile(base,      r, c, a_i0, a_i1, a_b0, a_b1, hAf, gAf, w2f, out);
  compute_tile(base + 16, r, c, b_i0, b_i1, b_b0, b_b1, hAf, gAf, w2f, out);
}

extern "C" void kernel_launch(void* const* d_in, const int* in_sizes, int n_in,
                              void* d_out, int out_size, void* d_ws, size_t ws_size,
                              hipStream_t stream) {
  const float* img  = (const float*)d_in[0];
  const float* txt  = (const float*)d_in[1];
  const float* Wiv  = (const float*)d_in[6];
  const float* biv  = (const float*)d_in[7];
  const float* Wtv  = (const float*)d_in[12];
  const float* btv  = (const float*)d_in[13];
  const float* Wisv = (const float*)d_in[18];
  const float* bisv = (const float*)d_in[19];
  const float* Wtsv = (const float*)d_in[24];
  const float* btsv = (const float*)d_in[25];
  const float* Wm1  = (const float*)d_in[26];
  const float* bm1  = (const float*)d_in[27];
  const float* Wm2  = (const float*)d_in[28];
  const float* bm2  = (const float*)d_in[29];
  const float* Wg   = (const float*)d_in[30];
  const float* bg   = (const float*)d_in[31];
  float* out = (float*)d_out;
  unsigned short* wsbf = (unsigned short*)d_ws;  // 64*18*8 bf16 = 18432 B

  const int nrows = in_sizes[0] / 40;  // 262144

  hipLaunchKernelGGL(fold_kernel, dim3(1), dim3(1024), 0, stream,
                     Wiv, biv, Wtv, btv, Wisv, bisv, Wtsv, btsv,
                     Wm1, bm1, Wm2, bm2, Wg, bg, wsbf);

  const int grid = nrows / 128;  // 2048 blocks x 4 waves x 32 rows
  hipLaunchKernelGGL(mfma_main, dim3(grid), dim3(256), 0, stream,
                     img, txt, wsbf, out);
}

// Round 6
// 42.169 us; speedup vs baseline: 2.3464x; 2.3464x over previous
//
#include <hip/hip_runtime.h>
#include <hip/hip_bf16.h>
#include <math.h>

typedef __attribute__((ext_vector_type(8))) short short8v;  // 8 bf16 in 4 VGPRs
typedef __attribute__((ext_vector_type(4))) float f32x4;

__device__ inline unsigned short f2bf(float f) {
  return __builtin_bit_cast(unsigned short, __float2bfloat16(f));
}

// ---------------------------------------------------------------------------
// fold_packed: computes the pre-packed bf16 weight fragments DIRECTLY —
// each of the 64*18*8 = 9216 packed elements is an independent dot product
// over the original (tiny, L2-resident) weights. 36 blocks x 256 threads,
// one element per thread, no LDS, no barriers.
// Layout: wsbf[lane][frag 0..17][elem 0..7] bf16, lane = 16*c + r:
//   frags 0..5  : hAf[go][f] = hA[(16go+r)][32f + 8c + e]
//   frags 6..11 : gAf[go][f]   same from gA
//   frags 12..17: w2f[go][f]   delta-permuted W2 (+ b2 at f=1,e=4)
// hA/gA col j: 0..39 img coeff, 40..59 txt coeff, 60 bias, 61..63 zero.
// ---------------------------------------------------------------------------
__global__ __launch_bounds__(256) void fold_packed(
    const float* __restrict__ Wiv, const float* __restrict__ biv,
    const float* __restrict__ Wtv, const float* __restrict__ btv,
    const float* __restrict__ Wisv, const float* __restrict__ bisv,
    const float* __restrict__ Wtsv, const float* __restrict__ btsv,
    const float* __restrict__ Wm1, const float* __restrict__ bm1,
    const float* __restrict__ Wm2, const float* __restrict__ bm2,
    const float* __restrict__ Wg, const float* __restrict__ bg,
    unsigned short* __restrict__ wsbf) {
  const int idx = blockIdx.x * 256 + threadIdx.x;
  if (idx >= 64 * 18 * 8) return;
  const int lane = idx / 144;
  const int f18 = (idx >> 3) % 18;
  const int e = idx & 7;
  const int r = lane & 15, c = lane >> 4;

  float v = 0.f;
  if (f18 < 12) {
    const bool isH = (f18 < 6);
    const int q = isH ? f18 : f18 - 6;
    const int go = q >> 1, f = q & 1;
    const int row = go * 16 + r;
    const int j = f * 32 + c * 8 + e;
    if (isH) {
      if (j < 40) {
        for (int k = 0; k < 48; ++k) v += Wm1[row * 144 + 48 + k] * Wtv[k * 40 + j];
        for (int k = 0; k < 24; ++k) v += Wm1[row * 144 + 96 + k] * Wisv[k * 40 + j];
      } else if (j < 60) {
        const int jj = j - 40;
        for (int k = 0; k < 48; ++k) v += Wm1[row * 144 + k] * Wiv[k * 20 + jj];
        for (int k = 0; k < 24; ++k) v += Wm1[row * 144 + 120 + k] * Wtsv[k * 20 + jj];
      } else if (j == 60) {
        v = bm1[row];
        for (int k = 0; k < 48; ++k) v += Wm1[row * 144 + k] * biv[k];
        for (int k = 0; k < 48; ++k) v += Wm1[row * 144 + 48 + k] * btv[k];
        for (int k = 0; k < 24; ++k) v += Wm1[row * 144 + 96 + k] * bisv[k];
        for (int k = 0; k < 24; ++k) v += Wm1[row * 144 + 120 + k] * btsv[k];
      }
    } else {
      if (j < 40) {
        for (int k = 0; k < 48; ++k) v += Wg[row * 96 + 48 + k] * Wtv[k * 40 + j];
      } else if (j < 60) {
        const int jj = j - 40;
        for (int k = 0; k < 48; ++k) v += Wg[row * 96 + k] * Wiv[k * 20 + jj];
      } else if (j == 60) {
        v = bg[row];
        for (int k = 0; k < 48; ++k) v += Wg[row * 96 + k] * biv[k];
        for (int k = 0; k < 48; ++k) v += Wg[row * 96 + 48 + k] * btv[k];
      }
    }
  } else {
    const int q = f18 - 12;
    const int f = q & 1;
    const int row = (q >> 1) * 16 + r;
    if (f == 0) {
      const int col = (e < 4) ? (4 * c + e) : (16 + 4 * c + (e - 4));
      v = Wm2[row * 48 + col];
    } else {
      if (e < 4) v = Wm2[row * 48 + 32 + 4 * c + e];
      else if (e == 4) v = bm2[row];
    }
  }
  wsbf[idx] = f2bf(v);
}

// ---------------------------------------------------------------------------
// mfma_main (unchanged from round 5 — measured ~23 us): 4 waves x 32 rows,
// grid 2048. Pre-packed weights resident in VGPRs; both tiles' X loads
// issued up front; no LDS, no barriers.
// ---------------------------------------------------------------------------
__device__ __forceinline__ short8v packX(float4 a, float4 b) {
  short8v sv;
  sv[0] = (short)f2bf(a.x); sv[1] = (short)f2bf(a.y);
  sv[2] = (short)f2bf(a.z); sv[3] = (short)f2bf(a.w);
  sv[4] = (short)f2bf(b.x); sv[5] = (short)f2bf(b.y);
  sv[6] = (short)f2bf(b.z); sv[7] = (short)f2bf(b.w);
  return sv;
}

__device__ __forceinline__ void compute_tile(
    int rowbase, int r, int c,
    float4 i0, float4 i1, float4 b0, float4 b1,
    const short8v (&hAf)[3][2], const short8v (&gAf)[3][2],
    const short8v (&w2f)[3][2], float* __restrict__ out) {
  const f32x4 z = {0.f, 0.f, 0.f, 0.f};
  short8v xa0 = packX(i0, i1);
  short8v xa1 = packX(b0, b1);

  f32x4 hacc[3], gacc[3];
#pragma unroll
  for (int go = 0; go < 3; ++go)
    hacc[go] = __builtin_amdgcn_mfma_f32_16x16x32_bf16(
        hAf[go][1], xa1,
        __builtin_amdgcn_mfma_f32_16x16x32_bf16(hAf[go][0], xa0, z, 0, 0, 0),
        0, 0, 0);
#pragma unroll
  for (int go = 0; go < 3; ++go)
    gacc[go] = __builtin_amdgcn_mfma_f32_16x16x32_bf16(
        gAf[go][1], xa1,
        __builtin_amdgcn_mfma_f32_16x16x32_bf16(gAf[go][0], xa0, z, 0, 0, 0),
        0, 0, 0);

  short8v hb0, hb1;
#pragma unroll
  for (int j = 0; j < 4; ++j) {
    hb0[j]     = (short)f2bf(fmaxf(hacc[0][j], 0.f));
    hb0[j + 4] = (short)f2bf(fmaxf(hacc[1][j], 0.f));
    hb1[j]     = (short)f2bf(fmaxf(hacc[2][j], 0.f));
  }
  hb1[4] = (c == 3) ? (short)0x3F80 : (short)0;  // bias-1.0 in exactly one k-slot
  hb1[5] = 0; hb1[6] = 0; hb1[7] = 0;

  f32x4 oacc[3];
#pragma unroll
  for (int go = 0; go < 3; ++go)
    oacc[go] = __builtin_amdgcn_mfma_f32_16x16x32_bf16(
        w2f[go][1], hb1,
        __builtin_amdgcn_mfma_f32_16x16x32_bf16(w2f[go][0], hb0, z, 0, 0, 0),
        0, 0, 0);

  float* orow = out + (size_t)(rowbase + r) * 48;
#pragma unroll
  for (int go = 0; go < 3; ++go) {
    float4 v;
    v.x = fmaxf(oacc[go][0], 0.f) * __builtin_amdgcn_rcpf(1.f + __expf(-gacc[go][0]));
    v.y = fmaxf(oacc[go][1], 0.f) * __builtin_amdgcn_rcpf(1.f + __expf(-gacc[go][1]));
    v.z = fmaxf(oacc[go][2], 0.f) * __builtin_amdgcn_rcpf(1.f + __expf(-gacc[go][2]));
    v.w = fmaxf(oacc[go][3], 0.f) * __builtin_amdgcn_rcpf(1.f + __expf(-gacc[go][3]));
    *reinterpret_cast<float4*>(orow + 16 * go + 4 * c) = v;
  }
}

__global__ __launch_bounds__(256, 3) void mfma_main(
    const float* __restrict__ img, const float* __restrict__ txt,
    const unsigned short* __restrict__ wsbf, float* __restrict__ out) {
  const int tid = threadIdx.x;
  const int wave = tid >> 6;
  const int lane = tid & 63;
  const int r = lane & 15;
  const int c = lane >> 4;

  // resident pre-packed weight fragments: 18 x 16B contiguous per lane
  const short8v* wp = reinterpret_cast<const short8v*>(wsbf) + lane * 18;
  short8v hAf[3][2], gAf[3][2], w2f[3][2];
#pragma unroll
  for (int go = 0; go < 3; ++go) {
    hAf[go][0] = wp[go * 2 + 0];      hAf[go][1] = wp[go * 2 + 1];
    gAf[go][0] = wp[6 + go * 2 + 0];  gAf[go][1] = wp[6 + go * 2 + 1];
    w2f[go][0] = wp[12 + go * 2 + 0]; w2f[go][1] = wp[12 + go * 2 + 1];
  }

  const int base = blockIdx.x * 128 + wave * 32;  // 2 tiles of 16 rows

  // ---- issue ALL X loads for both tiles before any compute ----
  const float* pimg0 = img + (size_t)(base + r) * 40;
  const float* ptxt0 = txt + (size_t)(base + r) * 20;
  const float* pimg1 = pimg0 + 16 * 40;
  const float* ptxt1 = ptxt0 + 16 * 20;

  float4 a_i0 = *(const float4*)(pimg0 + c * 8);
  float4 a_i1 = *(const float4*)(pimg0 + c * 8 + 4);
  float4 b_i0 = *(const float4*)(pimg1 + c * 8);
  float4 b_i1 = *(const float4*)(pimg1 + c * 8 + 4);
  float4 a_b0, a_b1, b_b0, b_b1;
  if (c == 0) {
    a_b0 = *(const float4*)(pimg0 + 32); a_b1 = *(const float4*)(pimg0 + 36);
    b_b0 = *(const float4*)(pimg1 + 32); b_b1 = *(const float4*)(pimg1 + 36);
  } else if (c == 3) {
    a_b0 = *(const float4*)(ptxt0 + 16); b_b0 = *(const float4*)(ptxt1 + 16);
    a_b1 = make_float4(1.f, 0.f, 0.f, 0.f); b_b1 = make_float4(1.f, 0.f, 0.f, 0.f);
  } else {
    a_b0 = *(const float4*)(ptxt0 + (c - 1) * 8);
    a_b1 = *(const float4*)(ptxt0 + (c - 1) * 8 + 4);
    b_b0 = *(const float4*)(ptxt1 + (c - 1) * 8);
    b_b1 = *(const float4*)(ptxt1 + (c - 1) * 8 + 4);
  }

  compute_tile(base,      r, c, a_i0, a_i1, a_b0, a_b1, hAf, gAf, w2f, out);
  compute_tile(base + 16, r, c, b_i0, b_i1, b_b0, b_b1, hAf, gAf, w2f, out);
}

extern "C" void kernel_launch(void* const* d_in, const int* in_sizes, int n_in,
                              void* d_out, int out_size, void* d_ws, size_t ws_size,
                              hipStream_t stream) {
  const float* img  = (const float*)d_in[0];
  const float* txt  = (const float*)d_in[1];
  const float* Wiv  = (const float*)d_in[6];
  const float* biv  = (const float*)d_in[7];
  const float* Wtv  = (const float*)d_in[12];
  const float* btv  = (const float*)d_in[13];
  const float* Wisv = (const float*)d_in[18];
  const float* bisv = (const float*)d_in[19];
  const float* Wtsv = (const float*)d_in[24];
  const float* btsv = (const float*)d_in[25];
  const float* Wm1  = (const float*)d_in[26];
  const float* bm1  = (const float*)d_in[27];
  const float* Wm2  = (const float*)d_in[28];
  const float* bm2  = (const float*)d_in[29];
  const float* Wg   = (const float*)d_in[30];
  const float* bg   = (const float*)d_in[31];
  float* out = (float*)d_out;
  unsigned short* wsbf = (unsigned short*)d_ws;  // 64*18*8 bf16 = 18432 B

  const int nrows = in_sizes[0] / 40;  // 262144

  hipLaunchKernelGGL(fold_packed, dim3(36), dim3(256), 0, stream,
                     Wiv, biv, Wtv, btv, Wisv, bisv, Wtsv, btsv,
                     Wm1, bm1, Wm2, bm2, Wg, bg, wsbf);

  const int grid = nrows / 128;  // 2048 blocks x 4 waves x 32 rows
  hipLaunchKernelGGL(mfma_main, dim3(grid), dim3(256), 0, stream,
                     img, txt, wsbf, out);
}

// Round 7
// 38.482 us; speedup vs baseline: 2.5711x; 1.0958x over previous
//
#include <hip/hip_runtime.h>
#include <hip/hip_bf16.h>
#include <math.h>

typedef __attribute__((ext_vector_type(8))) short short8v;  // 8 bf16 in 4 VGPRs
typedef __attribute__((ext_vector_type(4))) float f32x4;

__device__ inline unsigned short f2bf(float f) {
  return __builtin_bit_cast(unsigned short, __float2bfloat16(f));
}

// ---------------------------------------------------------------------------
// fold_packed (unchanged from round 6): pre-packed bf16 weight fragments,
// one element per thread, 36 blocks x 256, no LDS/sync.
// Layout: wsbf[lane][frag 0..17][elem 0..7] bf16, lane = 16*c + r:
//   frags 0..5  : hAf[go][f] = hA[(16go+r)][32f + 8c + e]
//   frags 6..11 : gAf[go][f]   same from gA
//   frags 12..17: w2f[go][f]   delta-permuted W2 (+ b2 at f=1,e=4)
// hA/gA col j: 0..39 img coeff, 40..59 txt coeff, 60 bias, 61..63 zero.
// ---------------------------------------------------------------------------
__global__ __launch_bounds__(256) void fold_packed(
    const float* __restrict__ Wiv, const float* __restrict__ biv,
    const float* __restrict__ Wtv, const float* __restrict__ btv,
    const float* __restrict__ Wisv, const float* __restrict__ bisv,
    const float* __restrict__ Wtsv, const float* __restrict__ btsv,
    const float* __restrict__ Wm1, const float* __restrict__ bm1,
    const float* __restrict__ Wm2, const float* __restrict__ bm2,
    const float* __restrict__ Wg, const float* __restrict__ bg,
    unsigned short* __restrict__ wsbf) {
  const int idx = blockIdx.x * 256 + threadIdx.x;
  if (idx >= 64 * 18 * 8) return;
  const int lane = idx / 144;
  const int f18 = (idx >> 3) % 18;
  const int e = idx & 7;
  const int r = lane & 15, c = lane >> 4;

  float v = 0.f;
  if (f18 < 12) {
    const bool isH = (f18 < 6);
    const int q = isH ? f18 : f18 - 6;
    const int go = q >> 1, f = q & 1;
    const int row = go * 16 + r;
    const int j = f * 32 + c * 8 + e;
    if (isH) {
      if (j < 40) {
        for (int k = 0; k < 48; ++k) v += Wm1[row * 144 + 48 + k] * Wtv[k * 40 + j];
        for (int k = 0; k < 24; ++k) v += Wm1[row * 144 + 96 + k] * Wisv[k * 40 + j];
      } else if (j < 60) {
        const int jj = j - 40;
        for (int k = 0; k < 48; ++k) v += Wm1[row * 144 + k] * Wiv[k * 20 + jj];
        for (int k = 0; k < 24; ++k) v += Wm1[row * 144 + 120 + k] * Wtsv[k * 20 + jj];
      } else if (j == 60) {
        v = bm1[row];
        for (int k = 0; k < 48; ++k) v += Wm1[row * 144 + k] * biv[k];
        for (int k = 0; k < 48; ++k) v += Wm1[row * 144 + 48 + k] * btv[k];
        for (int k = 0; k < 24; ++k) v += Wm1[row * 144 + 96 + k] * bisv[k];
        for (int k = 0; k < 24; ++k) v += Wm1[row * 144 + 120 + k] * btsv[k];
      }
    } else {
      if (j < 40) {
        for (int k = 0; k < 48; ++k) v += Wg[row * 96 + 48 + k] * Wtv[k * 40 + j];
      } else if (j < 60) {
        const int jj = j - 40;
        for (int k = 0; k < 48; ++k) v += Wg[row * 96 + k] * Wiv[k * 20 + jj];
      } else if (j == 60) {
        v = bg[row];
        for (int k = 0; k < 48; ++k) v += Wg[row * 96 + k] * biv[k];
        for (int k = 0; k < 48; ++k) v += Wg[row * 96 + 48 + k] * btv[k];
      }
    }
  } else {
    const int q = f18 - 12;
    const int f = q & 1;
    const int row = (q >> 1) * 16 + r;
    if (f == 0) {
      const int col = (e < 4) ? (4 * c + e) : (16 + 4 * c + (e - 4));
      v = Wm2[row * 48 + col];
    } else {
      if (e < 4) v = Wm2[row * 48 + 32 + 4 * c + e];
      else if (e == 4) v = bm2[row];
    }
  }
  wsbf[idx] = f2bf(v);
}

// ---------------------------------------------------------------------------
// mfma_main: 4 waves x 64 rows (4 tiles of 16), grid 1024.
// __launch_bounds__(256, 2): VGPR budget 256 so the 72 weight VGPRs stay
// resident AND all 32 X-loads issue up front and stay in flight (~26 KB/wave
// of MLP). Round-6 post-mortem: at 68 VGPRs the compiler serialized the
// memory stream (41 us, 2 TB/s); this is the single-variable fix.
// ---------------------------------------------------------------------------
__device__ __forceinline__ short8v packX(float4 a, float4 b) {
  short8v sv;
  sv[0] = (short)f2bf(a.x); sv[1] = (short)f2bf(a.y);
  sv[2] = (short)f2bf(a.z); sv[3] = (short)f2bf(a.w);
  sv[4] = (short)f2bf(b.x); sv[5] = (short)f2bf(b.y);
  sv[6] = (short)f2bf(b.z); sv[7] = (short)f2bf(b.w);
  return sv;
}

__device__ __forceinline__ void compute_tile(
    int rowbase, int r, int c,
    float4 i0, float4 i1, float4 b0, float4 b1,
    const short8v (&hAf)[3][2], const short8v (&gAf)[3][2],
    const short8v (&w2f)[3][2], float* __restrict__ out) {
  const f32x4 z = {0.f, 0.f, 0.f, 0.f};
  short8v xa0 = packX(i0, i1);
  short8v xa1 = packX(b0, b1);

  f32x4 hacc[3], gacc[3];
#pragma unroll
  for (int go = 0; go < 3; ++go)
    hacc[go] = __builtin_amdgcn_mfma_f32_16x16x32_bf16(
        hAf[go][1], xa1,
        __builtin_amdgcn_mfma_f32_16x16x32_bf16(hAf[go][0], xa0, z, 0, 0, 0),
        0, 0, 0);
#pragma unroll
  for (int go = 0; go < 3; ++go)
    gacc[go] = __builtin_amdgcn_mfma_f32_16x16x32_bf16(
        gAf[go][1], xa1,
        __builtin_amdgcn_mfma_f32_16x16x32_bf16(gAf[go][0], xa0, z, 0, 0, 0),
        0, 0, 0);

  short8v hb0, hb1;
#pragma unroll
  for (int j = 0; j < 4; ++j) {
    hb0[j]     = (short)f2bf(fmaxf(hacc[0][j], 0.f));
    hb0[j + 4] = (short)f2bf(fmaxf(hacc[1][j], 0.f));
    hb1[j]     = (short)f2bf(fmaxf(hacc[2][j], 0.f));
  }
  hb1[4] = (c == 3) ? (short)0x3F80 : (short)0;  // bias-1.0 in exactly one k-slot
  hb1[5] = 0; hb1[6] = 0; hb1[7] = 0;

  f32x4 oacc[3];
#pragma unroll
  for (int go = 0; go < 3; ++go)
    oacc[go] = __builtin_amdgcn_mfma_f32_16x16x32_bf16(
        w2f[go][1], hb1,
        __builtin_amdgcn_mfma_f32_16x16x32_bf16(w2f[go][0], hb0, z, 0, 0, 0),
        0, 0, 0);

  float* orow = out + (size_t)(rowbase + r) * 48;
#pragma unroll
  for (int go = 0; go < 3; ++go) {
    float4 v;
    v.x = fmaxf(oacc[go][0], 0.f) * __builtin_amdgcn_rcpf(1.f + __expf(-gacc[go][0]));
    v.y = fmaxf(oacc[go][1], 0.f) * __builtin_amdgcn_rcpf(1.f + __expf(-gacc[go][1]));
    v.z = fmaxf(oacc[go][2], 0.f) * __builtin_amdgcn_rcpf(1.f + __expf(-gacc[go][2]));
    v.w = fmaxf(oacc[go][3], 0.f) * __builtin_amdgcn_rcpf(1.f + __expf(-gacc[go][3]));
    *reinterpret_cast<float4*>(orow + 16 * go + 4 * c) = v;
  }
}

__global__ __launch_bounds__(256, 2) void mfma_main(
    const float* __restrict__ img, const float* __restrict__ txt,
    const unsigned short* __restrict__ wsbf, float* __restrict__ out) {
  const int tid = threadIdx.x;
  const int wave = tid >> 6;
  const int lane = tid & 63;
  const int r = lane & 15;
  const int c = lane >> 4;

  // resident pre-packed weight fragments: 18 x 16B contiguous per lane
  const short8v* wp = reinterpret_cast<const short8v*>(wsbf) + lane * 18;
  short8v hAf[3][2], gAf[3][2], w2f[3][2];
#pragma unroll
  for (int go = 0; go < 3; ++go) {
    hAf[go][0] = wp[go * 2 + 0];      hAf[go][1] = wp[go * 2 + 1];
    gAf[go][0] = wp[6 + go * 2 + 0];  gAf[go][1] = wp[6 + go * 2 + 1];
    w2f[go][0] = wp[12 + go * 2 + 0]; w2f[go][1] = wp[12 + go * 2 + 1];
  }

  const int base = blockIdx.x * 256 + wave * 64;  // 4 tiles of 16 rows

  // ---- issue ALL X loads for all 4 tiles before any compute ----
  float4 xi0[4], xi1[4], xb0[4], xb1[4];
#pragma unroll
  for (int t = 0; t < 4; ++t) {
    const float* pi = img + (size_t)(base + 16 * t + r) * 40;
    const float* pt = txt + (size_t)(base + 16 * t + r) * 20;
    xi0[t] = *(const float4*)(pi + c * 8);
    xi1[t] = *(const float4*)(pi + c * 8 + 4);
    if (c == 0) {
      xb0[t] = *(const float4*)(pi + 32);
      xb1[t] = *(const float4*)(pi + 36);
    } else if (c == 3) {
      xb0[t] = *(const float4*)(pt + 16);
      xb1[t] = make_float4(1.f, 0.f, 0.f, 0.f);
    } else {
      xb0[t] = *(const float4*)(pt + (c - 1) * 8);
      xb1[t] = *(const float4*)(pt + (c - 1) * 8 + 4);
    }
  }

#pragma unroll
  for (int t = 0; t < 4; ++t)
    compute_tile(base + 16 * t, r, c, xi0[t], xi1[t], xb0[t], xb1[t],
                 hAf, gAf, w2f, out);
}

extern "C" void kernel_launch(void* const* d_in, const int* in_sizes, int n_in,
                              void* d_out, int out_size, void* d_ws, size_t ws_size,
                              hipStream_t stream) {
  const float* img  = (const float*)d_in[0];
  const float* txt  = (const float*)d_in[1];
  const float* Wiv  = (const float*)d_in[6];
  const float* biv  = (const float*)d_in[7];
  const float* Wtv  = (const float*)d_in[12];
  const float* btv  = (const float*)d_in[13];
  const float* Wisv = (const float*)d_in[18];
  const float* bisv = (const float*)d_in[19];
  const float* Wtsv = (const float*)d_in[24];
  const float* btsv = (const float*)d_in[25];
  const float* Wm1  = (const float*)d_in[26];
  const float* bm1  = (const float*)d_in[27];
  const float* Wm2  = (const float*)d_in[28];
  const float* bm2  = (const float*)d_in[29];
  const float* Wg   = (const float*)d_in[30];
  const float* bg   = (const float*)d_in[31];
  float* out = (float*)d_out;
  unsigned short* wsbf = (unsigned short*)d_ws;  // 64*18*8 bf16 = 18432 B

  const int nrows = in_sizes[0] / 40;  // 262144

  hipLaunchKernelGGL(fold_packed, dim3(36), dim3(256), 0, stream,
                     Wiv, biv, Wtv, btv, Wisv, bisv, Wtsv, btsv,
                     Wm1, bm1, Wm2, bm2, Wg, bg, wsbf);

  const int grid = nrows / 256;  // 1024 blocks x 4 waves x 64 rows
  hipLaunchKernelGGL(mfma_main, dim3(grid), dim3(256), 0, stream,
                     img, txt, wsbf, out);
}